// Round 15
// baseline (470.583 us; speedup 1.0000x reference)
//
#include <hip/hip_runtime.h>
#include <cstddef>
#include <cstdint>
#include <cmath>

#define NH   16
#define DH   64
#define SLEN 2048
#define DM   1024

typedef __bf16          bf16x8   __attribute__((ext_vector_type(8)));
typedef float           f32x4    __attribute__((ext_vector_type(4)));
typedef unsigned short  ushort8  __attribute__((ext_vector_type(8)));
typedef unsigned short  ushort4v __attribute__((ext_vector_type(4)));
typedef unsigned int    uint4v   __attribute__((ext_vector_type(4)));

// ---- bf16 helpers (RTNE) ---------------------------------------------------
__device__ __forceinline__ unsigned short f2bf(float x) {
    union { float f; unsigned u; } v; v.f = x;
    unsigned r = v.u + 0x7fffu + ((v.u >> 16) & 1u);
    return (unsigned short)(r >> 16);
}
__device__ __forceinline__ float bf2f(unsigned short h) {
    union { unsigned u; float f; } v; v.u = ((unsigned)h) << 16;
    return v.f;
}
// packed RTNE convert: ret = {lo16: bf16(a), hi16: bf16(b)}
__device__ __forceinline__ unsigned cvt_pk_bf16(float a, float b) {
    unsigned r;
    asm("v_cvt_pk_bf16_f32 %0, %1, %2" : "=v"(r) : "v"(a), "v"(b));
    return r;
}

__device__ __forceinline__ f32x4 mfma16(ushort8 a, ushort8 b, f32x4 c) {
    return __builtin_amdgcn_mfma_f32_16x16x32_bf16(
        __builtin_bit_cast(bf16x8, a), __builtin_bit_cast(bf16x8, b), c, 0, 0, 0);
}
__device__ __forceinline__ f32x4 mfma16u(uint4v a, ushort8 b, f32x4 c) {
    return __builtin_amdgcn_mfma_f32_16x16x32_bf16(
        __builtin_bit_cast(bf16x8, a), __builtin_bit_cast(bf16x8, b), c, 0, 0, 0);
}

// ---------------------------------------------------------------------------
// Convert x (4M floats) and the 4 weight matrices (1M floats each) into
// hi/lo bf16 pairs.
// ---------------------------------------------------------------------------
__global__ __launch_bounds__(256)
void convert_hilo(const float* __restrict__ x,
                  const float* __restrict__ wq, const float* __restrict__ wk,
                  const float* __restrict__ wv, const float* __restrict__ wo,
                  unsigned short* __restrict__ xh, unsigned short* __restrict__ xl,
                  unsigned short* __restrict__ wh, unsigned short* __restrict__ wl)
{
    const unsigned c = blockIdx.x * 256 + threadIdx.x;
    const float* src;
    unsigned short *dh, *dl;
    size_t off;
    if (c < 1048576u) {
        src = x; dh = xh; dl = xl; off = c;
    } else {
        unsigned t = c - 1048576u;
        unsigned wsel = t >> 18;
        off = t & 262143u;
        src  = (wsel == 0) ? wq : (wsel == 1) ? wk : (wsel == 2) ? wv : wo;
        dh = wh + ((size_t)wsel << 20);
        dl = wl + ((size_t)wsel << 20);
    }
    float4 v = *(const float4*)(src + off * 4);
    float a[4] = {v.x, v.y, v.z, v.w};
    ushort4v h, l;
    #pragma unroll
    for (int i = 0; i < 4; ++i) {
        unsigned short hi = f2bf(a[i]);
        h[i] = hi;
        l[i] = f2bf(a[i] - bf2f(hi));
    }
    *(ushort4v*)(dh + off * 4) = h;
    *(ushort4v*)(dl + off * 4) = l;
}

// ---------------------------------------------------------------------------
// Split-bf16 GEMM: C[M=4096,N=1024] = (A @ W^T + bias) * scale, 3x bf16 MFMA.
// MODE 0: fp32 row-major [M,N]
// MODE 1: hi/lo bf16 to [b,h,s,d] via LDS-transposed coalesced epilogue (Q,K)
// MODE 2: hi/lo bf16 to [b,h,d,s] via LDS-transposed coalesced epilogue (V)
// ---------------------------------------------------------------------------
template<int MODE>
__global__ __launch_bounds__(256, 1)
void gemm_split(const unsigned short* __restrict__ Ahi, const unsigned short* __restrict__ Alo,
                const unsigned short* __restrict__ Whi, const unsigned short* __restrict__ Wlo,
                const float* __restrict__ bias, const float scale, float* __restrict__ outF,
                unsigned short* __restrict__ outH, unsigned short* __restrict__ outL)
{
    constexpr int K = DM;
    __shared__ __align__(16) char smem[40960];
    auto sAh = (unsigned short(*)[40])(smem);
    auto sAl = (unsigned short(*)[40])(smem + 10240);
    auto sBh = (unsigned short(*)[40])(smem + 20480);
    auto sBl = (unsigned short(*)[40])(smem + 30720);

    const int tid  = threadIdx.x;
    const int bm   = blockIdx.x * 128;
    const int bn   = blockIdx.y * 128;
    const int wid  = tid >> 6;
    const int lane = tid & 63;
    const int wm   = (wid >> 1) * 64;
    const int wn   = (wid & 1) * 64;

    const int r0 = tid >> 2;
    const int c0 = (tid & 3) * 8;

    const unsigned short* pAh0 = Ahi + (size_t)(bm + r0) * K + c0;
    const unsigned short* pAl0 = Alo + (size_t)(bm + r0) * K + c0;
    const unsigned short* pBh0 = Whi + (size_t)(bn + r0) * K + c0;
    const unsigned short* pBl0 = Wlo + (size_t)(bn + r0) * K + c0;
    const size_t rstep = (size_t)64 * K;

    ushort8 vah0 = *(const ushort8*)(pAh0), vah1 = *(const ushort8*)(pAh0 + rstep);
    ushort8 val0 = *(const ushort8*)(pAl0), val1 = *(const ushort8*)(pAl0 + rstep);
    ushort8 vbh0 = *(const ushort8*)(pBh0), vbh1 = *(const ushort8*)(pBh0 + rstep);
    ushort8 vbl0 = *(const ushort8*)(pBl0), vbl1 = *(const ushort8*)(pBl0 + rstep);

    f32x4 acc[4][4];
    #pragma unroll
    for (int i = 0; i < 4; ++i)
        #pragma unroll
        for (int j = 0; j < 4; ++j)
            acc[i][j] = (f32x4)0.0f;

    const int fr = lane & 15;
    const int kq = (lane >> 4) * 8;

    for (int k0 = 0; k0 < K; k0 += 32) {
        __syncthreads();
        *(ushort8*)&sAh[r0][c0]      = vah0;  *(ushort8*)&sAh[r0 + 64][c0] = vah1;
        *(ushort8*)&sAl[r0][c0]      = val0;  *(ushort8*)&sAl[r0 + 64][c0] = val1;
        *(ushort8*)&sBh[r0][c0]      = vbh0;  *(ushort8*)&sBh[r0 + 64][c0] = vbh1;
        *(ushort8*)&sBl[r0][c0]      = vbl0;  *(ushort8*)&sBl[r0 + 64][c0] = vbl1;
        __syncthreads();

        if (k0 + 32 < K) {
            const int kn = k0 + 32;
            vah0 = *(const ushort8*)(pAh0 + kn);  vah1 = *(const ushort8*)(pAh0 + rstep + kn);
            val0 = *(const ushort8*)(pAl0 + kn);  val1 = *(const ushort8*)(pAl0 + rstep + kn);
            vbh0 = *(const ushort8*)(pBh0 + kn);  vbh1 = *(const ushort8*)(pBh0 + rstep + kn);
            vbl0 = *(const ushort8*)(pBl0 + kn);  vbl1 = *(const ushort8*)(pBl0 + rstep + kn);
        }

        ushort8 afh[4], afl[4], bfh[4], bfl[4];
        #pragma unroll
        for (int i = 0; i < 4; ++i) {
            afh[i] = *(const ushort8*)&sAh[wm + i * 16 + fr][kq];
            afl[i] = *(const ushort8*)&sAl[wm + i * 16 + fr][kq];
            bfh[i] = *(const ushort8*)&sBh[wn + i * 16 + fr][kq];
            bfl[i] = *(const ushort8*)&sBl[wn + i * 16 + fr][kq];
        }

        #pragma unroll
        for (int i = 0; i < 4; ++i)
            #pragma unroll
            for (int j = 0; j < 4; ++j) {
                acc[i][j] = mfma16(afh[i], bfh[j], acc[i][j]);
                acc[i][j] = mfma16(afh[i], bfl[j], acc[i][j]);
                acc[i][j] = mfma16(afl[i], bfh[j], acc[i][j]);
            }
    }

    const int bb2 = bm >> 11;       // batch
    const int sm  = bm & 2047;      // seq offset within batch

    if (MODE == 1) {
        // Coalesced [b,h,s,d] epilogue: stage 128(m) x 64(d) f32 per n-half
        // through LDS, then write rows with d contiguous (16B hi/lo stores).
        float (*sT)[68] = (float(*)[68])smem;
        #pragma unroll
        for (int ph = 0; ph < 2; ++ph) {
            __syncthreads();
            if ((wid & 1) == ph) {
                #pragma unroll
                for (int j = 0; j < 4; ++j) {
                    const float bs = bias[bn + ph * 64 + j * 16 + fr];
                    #pragma unroll
                    for (int i = 0; i < 4; ++i)
                        #pragma unroll
                        for (int q = 0; q < 4; ++q)
                            sT[wm + i * 16 + (lane >> 4) * 4 + q][j * 16 + fr] =
                                (acc[i][j][q] + bs) * scale;
                }
            }
            __syncthreads();
            const int head = (bn + ph * 64) >> 6;
            const int r  = tid >> 1;          // 0..127 (m row)
            const int cc = (tid & 1) * 32;    // 0 / 32 (d)
            const size_t gb = ((((size_t)bb2 * NH + head) * SLEN) + sm + r) * DH + cc;
            #pragma unroll
            for (int u = 0; u < 4; ++u) {
                float4 f0 = *(const float4*)&sT[r][cc + u * 8];
                float4 f1 = *(const float4*)&sT[r][cc + u * 8 + 4];
                float fe[8] = {f0.x, f0.y, f0.z, f0.w, f1.x, f1.y, f1.z, f1.w};
                ushort8 hv, lv;
                #pragma unroll
                for (int e = 0; e < 8; ++e) {
                    const unsigned short vh = f2bf(fe[e]);
                    hv[e] = vh;
                    lv[e] = f2bf(fe[e] - bf2f(vh));
                }
                *(ushort8*)(outH + gb + u * 8) = hv;
                *(ushort8*)(outL + gb + u * 8) = lv;
            }
        }
        return;
    }

    if (MODE == 2) {
        // Coalesced V^T epilogue: stage 64(n) x 128(m) f32 halves through LDS,
        // then store rows with s contiguous (16B hi/lo stores).
        float (*sT)[132] = (float(*)[132])smem;
        #pragma unroll
        for (int ph = 0; ph < 2; ++ph) {
            __syncthreads();
            if ((wid & 1) == ph) {
                #pragma unroll
                for (int j = 0; j < 4; ++j) {
                    const float bs = bias[bn + ph * 64 + j * 16 + fr];
                    #pragma unroll
                    for (int i = 0; i < 4; ++i) {
                        float4 v4;
                        v4.x = acc[i][j][0] + bs;
                        v4.y = acc[i][j][1] + bs;
                        v4.z = acc[i][j][2] + bs;
                        v4.w = acc[i][j][3] + bs;
                        *(float4*)&sT[j * 16 + fr][wm + i * 16 + (lane >> 4) * 4] = v4;
                    }
                }
            }
            __syncthreads();
            #pragma unroll
            for (int half = 0; half < 2; ++half) {
                const int r  = (tid >> 3) + half * 32;
                const int cc = (tid & 7) * 16;
                const int n  = bn + ph * 64 + r;
                const size_t gb = ((((size_t)bb2 * NH + (n >> 6)) * DH) + (n & 63)) * SLEN + sm + cc;
                #pragma unroll
                for (int u = 0; u < 2; ++u) {
                    float4 f0 = *(const float4*)&sT[r][cc + u * 8];
                    float4 f1 = *(const float4*)&sT[r][cc + u * 8 + 4];
                    float fe[8] = {f0.x, f0.y, f0.z, f0.w, f1.x, f1.y, f1.z, f1.w};
                    ushort8 hv, lv;
                    #pragma unroll
                    for (int e = 0; e < 8; ++e) {
                        const unsigned short vh = f2bf(fe[e]);
                        hv[e] = vh;
                        lv[e] = f2bf(fe[e] - bf2f(vh));
                    }
                    *(ushort8*)(outH + gb + u * 8) = hv;
                    *(ushort8*)(outL + gb + u * 8) = lv;
                }
            }
        }
        return;
    }

    // MODE 0 epilogue: D layout col = lane&15, row = (lane>>4)*4 + q
    #pragma unroll
    for (int j = 0; j < 4; ++j) {
        const int n = bn + wn + j * 16 + fr;
        const float bs = bias[n];
        #pragma unroll
        for (int i = 0; i < 4; ++i) {
            #pragma unroll
            for (int q = 0; q < 4; ++q) {
                const int m = bm + wm + i * 16 + (lane >> 4) * 4 + q;
                outF[(size_t)m * DM + n] = (acc[i][j][q] + bs) * scale;
            }
        }
    }
}

// ---------------------------------------------------------------------------
// Flash attention via split-bf16 MFMA, KVBLK=32.
// One block per (b, h, 64-row q tile), 4 waves x 16 q rows.
// LDS 30KB -> 5 blocks/CU. K tile [32 kv][88] (176B rows: start bank
// (12fr+4g)%32 -> 2-way only), Vt tile [64 d][40] (2-way), P via wave-private
// fp32 LDS. P hi/lo split with v_cvt_pk_bf16_f32 (24 VALU vs ~80 scalar).
// 1/sqrt(64) pre-folded into Q by the Q projection (scale=0.125).
// ---------------------------------------------------------------------------
__global__ __launch_bounds__(256, 5)
void flash_attn_mfma(const unsigned short* __restrict__ Qh, const unsigned short* __restrict__ Ql,
                     const unsigned short* __restrict__ Kh, const unsigned short* __restrict__ Kl,
                     const unsigned short* __restrict__ Vth, const unsigned short* __restrict__ Vtl,
                     unsigned short* __restrict__ Ohi, unsigned short* __restrict__ Olo)
{
    __shared__ unsigned short sKh[32][88], sKl[32][88];   // [kv][d]   176B rows
    __shared__ unsigned short sVh[64][40], sVl[64][40];   // [d][kv]    80B rows
    __shared__ float sP[4][16][36];                       // per wave [q][kv]

    const int tid  = threadIdx.x;
    const int wid  = tid >> 6;
    const int lane = tid & 63;
    const int fr   = lane & 15;
    const int g    = lane >> 4;
    const int kq   = g * 8;
    const int q0   = blockIdx.x * 64;
    const int h    = blockIdx.y;
    const int b    = blockIdx.z;
    const size_t hb = (((size_t)b) * NH + h) * (size_t)SLEN * DH;

    // staging mappings
    const int kr = tid & 31, kc = (tid >> 5) * 8;   // K: [32 kv][64 d]
    const int vr = tid >> 2, vc = (tid & 3) * 8;    // Vt: [64 d][32 kv]

    // Q fragments: row fr of this wave's 16-row tile
    ushort8 qh[2], ql[2];
    {
        const size_t qbase = hb + (size_t)(q0 + wid * 16 + fr) * DH;
        qh[0] = *(const ushort8*)&Qh[qbase + kq];
        qh[1] = *(const ushort8*)&Qh[qbase + 32 + kq];
        ql[0] = *(const ushort8*)&Ql[qbase + kq];
        ql[1] = *(const ushort8*)&Ql[qbase + 32 + kq];
    }

    float mx[4], li[4];
    f32x4 acc[4];                    // [d-frag]; reg r -> q row g*4+r
    #pragma unroll
    for (int r = 0; r < 4; ++r) { mx[r] = -INFINITY; li[r] = 0.0f; }
    #pragma unroll
    for (int j = 0; j < 4; ++j) acc[j] = (f32x4)0.0f;

    for (int t = 0; t < SLEN / 32; ++t) {
        __syncthreads();   // previous tile's K/Vt reads complete
        {
            const size_t kb = hb + (size_t)(t * 32 + kr) * DH + kc;
            *(ushort8*)&sKh[kr][kc] = *(const ushort8*)&Kh[kb];
            *(ushort8*)&sKl[kr][kc] = *(const ushort8*)&Kl[kb];
            const size_t vb = hb + (size_t)vr * SLEN + t * 32 + vc;
            *(ushort8*)&sVh[vr][vc] = *(const ushort8*)&Vth[vb];
            *(ushort8*)&sVl[vr][vc] = *(const ushort8*)&Vtl[vb];
        }
        __syncthreads();

        // S = Q K^T : per wave 16 q rows x 32 kv (2 col-frags)
        f32x4 s[2];
        s[0] = (f32x4)0.0f; s[1] = (f32x4)0.0f;
        #pragma unroll
        for (int j = 0; j < 2; ++j) {
            #pragma unroll
            for (int ks = 0; ks < 2; ++ks) {
                ushort8 kfh = *(const ushort8*)&sKh[j * 16 + fr][ks * 32 + kq];
                ushort8 kfl = *(const ushort8*)&sKl[j * 16 + fr][ks * 32 + kq];
                s[j] = mfma16(qh[ks], kfh, s[j]);
                s[j] = mfma16(qh[ks], kfl, s[j]);
                s[j] = mfma16(ql[ks], kfh, s[j]);
            }
        }

        // online softmax: lane's rows are g*4+r, cols j*16+fr
        float p[4][2];
        #pragma unroll
        for (int r = 0; r < 4; ++r) {
            const float v0 = s[0][r], v1 = s[1][r];
            float rm = fmaxf(v0, v1);
            #pragma unroll
            for (int off = 1; off < 16; off <<= 1)
                rm = fmaxf(rm, __shfl_xor(rm, off));
            const float mn   = fmaxf(mx[r], rm);
            const float corr = __expf(mx[r] - mn);
            mx[r] = mn;
            p[r][0] = __expf(v0 - mn);
            p[r][1] = __expf(v1 - mn);
            float rs = p[r][0] + p[r][1];
            #pragma unroll
            for (int off = 1; off < 16; off <<= 1)
                rs += __shfl_xor(rs, off);
            li[r] = li[r] * corr + rs;
            #pragma unroll
            for (int jd = 0; jd < 4; ++jd) acc[jd][r] *= corr;
        }

        // P -> wave-private LDS (in-wave DS ordering, no barrier needed)
        #pragma unroll
        for (int r = 0; r < 4; ++r)
            #pragma unroll
            for (int j = 0; j < 2; ++j)
                sP[wid][g * 4 + r][j * 16 + fr] = p[r][j];

        // O += P V : A = P[16q][32kv], B = Vt[d][kv]
        {
            float4 pa = *(const float4*)&sP[wid][fr][kq];
            float4 pb = *(const float4*)&sP[wid][fr][kq + 4];
            float pe[8] = {pa.x, pa.y, pa.z, pa.w, pb.x, pb.y, pb.z, pb.w};
            uint4v ph, pl;
            #pragma unroll
            for (int e = 0; e < 4; ++e) {
                const unsigned hp = cvt_pk_bf16(pe[2 * e], pe[2 * e + 1]);
                const float r0 = __uint_as_float(hp << 16);
                const float r1 = __uint_as_float(hp & 0xffff0000u);
                ph[e] = hp;
                pl[e] = cvt_pk_bf16(pe[2 * e] - r0, pe[2 * e + 1] - r1);
            }
            #pragma unroll
            for (int jd = 0; jd < 4; ++jd) {
                ushort8 vfh = *(const ushort8*)&sVh[jd * 16 + fr][kq];
                ushort8 vfl = *(const ushort8*)&sVl[jd * 16 + fr][kq];
                acc[jd] = mfma16u(ph, vfh, acc[jd]);
                acc[jd] = mfma16u(ph, vfl, acc[jd]);
                acc[jd] = mfma16u(pl, vfh, acc[jd]);
            }
        }
    }

    // epilogue: q = q0 + wid*16 + g*4 + r, d = jd*16 + fr; write hi/lo bf16
    #pragma unroll
    for (int r = 0; r < 4; ++r) {
        const float inv = 1.0f / li[r];
        const int q = q0 + wid * 16 + g * 4 + r;
        const size_t base = ((size_t)b * SLEN + q) * DM + h * DH;
        #pragma unroll
        for (int jd = 0; jd < 4; ++jd) {
            const float v = acc[jd][r] * inv;
            const unsigned short hh2 = f2bf(v);
            Ohi[base + jd * 16 + fr] = hh2;
            Olo[base + jd * 16 + fr] = f2bf(v - bf2f(hh2));
        }
    }
}

// ---------------------------------------------------------------------------
extern "C" void kernel_launch(void* const* d_in, const int* in_sizes, int n_in,
                              void* d_out, int out_size, void* d_ws, size_t ws_size,
                              hipStream_t stream)
{
    const float* x   = (const float*)d_in[0];
    const float* w_q = (const float*)d_in[1];
    const float* b_q = (const float*)d_in[2];
    const float* w_k = (const float*)d_in[3];
    const float* b_k = (const float*)d_in[4];
    const float* w_v = (const float*)d_in[5];
    const float* b_v = (const float*)d_in[6];
    const float* w_o = (const float*)d_in[7];
    const float* b_o = (const float*)d_in[8];
    float* out = (float*)d_out;

    // workspace (80 MB), all bf16:
    //   [0,8)   xh  (-> AO_hi after QKV)     [8,16)  xl (-> AO_lo)
    //   [16,24) wh[4]                        [24,32) wl[4]
    //   [32,40) Qh   [40,48) Ql   [48,56) Kh   [56,64) Kl
    //   [64,72) Vth  [72,80) Vtl
    char* w = (char*)d_ws;
    const size_t MB = 1024 * 1024;
    unsigned short* xh  = (unsigned short*)(w);
    unsigned short* xl  = (unsigned short*)(w + 8  * MB);
    unsigned short* wh  = (unsigned short*)(w + 16 * MB);
    unsigned short* wl  = (unsigned short*)(w + 24 * MB);
    unsigned short* Qh  = (unsigned short*)(w + 32 * MB);
    unsigned short* Ql  = (unsigned short*)(w + 40 * MB);
    unsigned short* Kh  = (unsigned short*)(w + 48 * MB);
    unsigned short* Kl  = (unsigned short*)(w + 56 * MB);
    unsigned short* Vth = (unsigned short*)(w + 64 * MB);
    unsigned short* Vtl = (unsigned short*)(w + 72 * MB);

    convert_hilo<<<8192, 256, 0, stream>>>(x, w_q, w_k, w_v, w_o, xh, xl, wh, wl);

    dim3 gg(2 * SLEN / 128, DM / 128);
    gemm_split<1><<<gg, 256, 0, stream>>>(xh, xl, wh + 0 * 1048576, wl + 0 * 1048576, b_q, 0.125f, nullptr, Qh, Ql);
    gemm_split<1><<<gg, 256, 0, stream>>>(xh, xl, wh + 1 * 1048576, wl + 1 * 1048576, b_k, 1.0f,   nullptr, Kh, Kl);
    gemm_split<2><<<gg, 256, 0, stream>>>(xh, xl, wh + 2 * 1048576, wl + 2 * 1048576, b_v, 1.0f,   nullptr, Vth, Vtl);

    dim3 ga(SLEN / 64, NH, 2);
    flash_attn_mfma<<<ga, 256, 0, stream>>>(Qh, Ql, Kh, Kl, Vth, Vtl, xh, xl);

    gemm_split<0><<<gg, 256, 0, stream>>>(xh, xl, wh + 3 * 1048576, wl + 3 * 1048576, b_o, 1.0f, out, nullptr, nullptr);
}